// Round 4
// baseline (537.349 us; speedup 1.0000x reference)
//
#include <hip/hip_runtime.h>
#include <hip/hip_bf16.h>
#include <cstddef>

#define T_LEN 50000

typedef __attribute__((ext_vector_type(8))) short bf16x8;
typedef __attribute__((ext_vector_type(4))) float f32x4;

__device__ __forceinline__ float sp_(float x){ return (x > 20.f) ? x : log1pf(expf(x)); }
__device__ __forceinline__ float gelu1(float x){ return 0.5f*x*(1.f + erff(x*0.7071067811865475f)); }

// ---------------- kernel 0: w_proj [160][100] fp32 -> wbf [160][128] bf16 (K zero-padded) ----
__global__ void k_cvtw(const float* __restrict__ wproj, __hip_bfloat16* __restrict__ wbf)
{
    int idx = blockIdx.x*256 + threadIdx.x;
    if (idx < 160*128) {
        int d = idx >> 7, i = idx & 127;
        float v = (i < 100) ? wproj[d*100 + i] : 0.f;
        wbf[idx] = __float2bfloat16(v);
    }
}

// ---------------- kernel 1: preprocessing chain -> xs bf16 [patch][128] + m_patch ----------
// block: 256 threads, tile = 500 t (20 patches), 2 t/thread. grid = 64*100.
// LDS 21.6 KB (abf/mtL alias the dead xb region) -> 7-block LDS cap; LB(256,5) caps VGPR.
__global__ __launch_bounds__(256, 5) void k_pre(
    const float* __restrict__ X, const float* __restrict__ Mq,
    const float* __restrict__ w_env, const float* __restrict__ w_bur,
    const float* __restrict__ syn, const float* __restrict__ wdw,
    const float* __restrict__ wpw,
    __hip_bfloat16* __restrict__ xs_out, float* __restrict__ mpatch)
{
    __shared__ __align__(16) char smem[21664];
    float4* xb            = (float4*)smem;                 // [665]: 532 entries, +1-per-4 pad
    float4* s1b           = (float4*)(smem + 10640);       // [635]: 508 entries padded
    unsigned char* maskb  = (unsigned char*)(smem + 20800);// [532]
    float* WnL            = (float*)(smem + 21344);        // [16]
    float4* SmLUT         = (float4*)(smem + 21408);       // [16]
    // aliases valid after phase 2 (xb dead):
    __hip_bfloat16* abf   = (__hip_bfloat16*)smem;         // [20*128]
    float* mtL            = (float*)(smem + 5120);         // [500]

    const int tid  = threadIdx.x;
    const int b    = blockIdx.x / 100;
    const int tile = blockIdx.x % 100;
    const int t0   = tile * 500;

    // ---- phase 1: load x = X*M (float4 over channels) into xb, build mask ----
    const float4* X4 = (const float4*)X + (size_t)b * T_LEN;
    const float4* M4 = (const float4*)Mq + (size_t)b * T_LEN;
    #pragma unroll
    for (int jj = 0; jj < 3; ++jj) {
        int idx = tid + jj*256;
        if (idx < 532) {
            int t = t0 - 16 + idx;
            float4 xv = make_float4(0.f,0.f,0.f,0.f);
            unsigned mk = 0u;
            if (t >= 0 && t < T_LEN) {
                float4 a = X4[t], m = M4[t];
                xv = make_float4(a.x*m.x, a.y*m.y, a.z*m.z, a.w*m.w);
                mk = (m.x>0.f?1u:0u) | (m.y>0.f?2u:0u) | (m.z>0.f?4u:0u) | (m.w>0.f?8u:0u);
            }
            xb[idx + (idx>>2)] = xv;
            maskb[idx] = (unsigned char)mk;
        }
    }
    if (tid < 4) {
        float w0 = sp_(syn[tid*4+0]), w1 = sp_(syn[tid*4+1]);
        float w2 = sp_(syn[tid*4+2]), w3 = sp_(syn[tid*4+3]);
        float inv = 1.f / fmaxf(w0+w1+w2+w3, 1e-6f);
        WnL[tid*4+0]=w0*inv; WnL[tid*4+1]=w1*inv; WnL[tid*4+2]=w2*inv; WnL[tid*4+3]=w3*inv;
    }
    __syncthreads();
    if (tid < 16) {
        float sm[4];
        #pragma unroll
        for (int m=0;m<4;++m) {
            float a = 0.f;
            #pragma unroll
            for (int c=0;c<4;++c) if (tid & (1<<c)) a += WnL[m*4+c];
            sm[m] = fminf(a, 1.f);
        }
        SmLUT[tid] = make_float4(sm[0],sm[1],sm[2],sm[3]);
    }
    __syncthreads();

    // ---- phase 2: env/burst/xm -> S1 for t in [t0-4, t0+504), 2 t/thread ----
    if (tid < 254) {
        float4 env[2], bur[2], xk[2];
        #pragma unroll
        for (int j=0;j<2;++j){ env[j]=make_float4(0,0,0,0); bur[j]=make_float4(0,0,0,0); }
        float4 xprev = make_float4(0,0,0,0);
        const int base  = 2*tid;
        const int gbase = t0 - 4 + base;
        #pragma unroll
        for (int s = -12; s <= 13; ++s) {
            int lt = base + (s+12);
            float4 xc = xb[lt + (lt>>2)];
            float4 ax = make_float4(fabsf(xc.x),fabsf(xc.y),fabsf(xc.z),fabsf(xc.w));
            if (s >= -4 && s <= 5) {
                int g = gbase + s;
                float4 dx;
                if (g <= 0 || g >= T_LEN) dx = make_float4(0,0,0,0);
                else dx = make_float4(xc.x-xprev.x, xc.y-xprev.y, xc.z-xprev.z, xc.w-xprev.w);
                float4 adx = make_float4(fabsf(dx.x),fabsf(dx.y),fabsf(dx.z),fabsf(dx.w));
                #pragma unroll
                for (int j=0;j<2;++j) {
                    int bk = s + 4 - j;
                    if (bk >= 0 && bk < 9) {
                        float b0=w_bur[bk], b1=w_bur[9+bk], b2=w_bur[18+bk], b3=w_bur[27+bk];
                        bur[j].x = fmaf(b0, adx.x, bur[j].x);
                        bur[j].y = fmaf(b1, adx.y, bur[j].y);
                        bur[j].z = fmaf(b2, adx.z, bur[j].z);
                        bur[j].w = fmaf(b3, adx.w, bur[j].w);
                    }
                }
            }
            #pragma unroll
            for (int j=0;j<2;++j) {
                int k = s + 12 - j;
                if (k >= 0 && k < 25) {
                    float e0=w_env[k], e1=w_env[25+k], e2=w_env[50+k], e3=w_env[75+k];
                    env[j].x = fmaf(e0, ax.x, env[j].x);
                    env[j].y = fmaf(e1, ax.y, env[j].y);
                    env[j].z = fmaf(e2, ax.z, env[j].z);
                    env[j].w = fmaf(e3, ax.w, env[j].w);
                }
            }
            if (s >= 0 && s <= 1) xk[s] = xc;
            xprev = xc;
        }
        #pragma unroll
        for (int j=0;j<2;++j) {
            int g = gbase + j;
            float4 xm = make_float4(
                0.9f*env[j].x + 0.6f*bur[j].x + 0.2f*xk[j].x,
                0.9f*env[j].y + 0.6f*bur[j].y + 0.2f*xk[j].y,
                0.9f*env[j].z + 0.6f*bur[j].z + 0.2f*xk[j].z,
                0.9f*env[j].w + 0.6f*bur[j].w + 0.2f*xk[j].w);
            float4 out = make_float4(0,0,0,0);
            if (g >= 0 && g < T_LEN) {
                out.x = WnL[0]*xm.x  + WnL[1]*xm.y  + WnL[2]*xm.z  + WnL[3]*xm.w;
                out.y = WnL[4]*xm.x  + WnL[5]*xm.y  + WnL[6]*xm.z  + WnL[7]*xm.w;
                out.z = WnL[8]*xm.x  + WnL[9]*xm.y  + WnL[10]*xm.z + WnL[11]*xm.w;
                out.w = WnL[12]*xm.x + WnL[13]*xm.y + WnL[14]*xm.z + WnL[15]*xm.w;
            }
            int ls = base + j;
            s1b[ls + (ls>>2)] = out;
        }
    }
    __syncthreads();   // xb dead from here; abf/mtL aliases become valid

    // ---- phase 3: pre-dw + gelu + pw + gelu, * Sm -> abf (bf16 A-layout); mtL ----
    for (int idx = tid; idx < 20*28; idx += 256) {   // zero K-pad i in [100,128)
        int p = idx / 28, i = 100 + idx % 28;
        abf[p*128 + i] = __float2bfloat16(0.f);
    }
    if (tid < 250) {
        float4 s2a[2];
        #pragma unroll
        for (int j=0;j<2;++j) s2a[j]=make_float4(0,0,0,0);
        const int base = 2*tid;
        #pragma unroll
        for (int s = -4; s <= 5; ++s) {
            int ls = base + s + 4;
            float4 sc = s1b[ls + (ls>>2)];
            #pragma unroll
            for (int j=0;j<2;++j) {
                int k = s + 4 - j;
                if (k >= 0 && k < 9) {
                    float d0=wdw[k], d1=wdw[9+k], d2=wdw[18+k], d3=wdw[27+k];
                    s2a[j].x = fmaf(d0, sc.x, s2a[j].x);
                    s2a[j].y = fmaf(d1, sc.y, s2a[j].y);
                    s2a[j].z = fmaf(d2, sc.z, s2a[j].z);
                    s2a[j].w = fmaf(d3, sc.w, s2a[j].w);
                }
            }
        }
        #pragma unroll
        for (int j=0;j<2;++j) {
            int t = base + j;              // local t in [0,500)
            float g0 = gelu1(s2a[j].x), g1 = gelu1(s2a[j].y);
            float g2 = gelu1(s2a[j].z), g3 = gelu1(s2a[j].w);
            float4 sm = SmLUT[maskb[t + 16]];
            int p = t / 25, k = t % 25;
            float smv[4] = {sm.x, sm.y, sm.z, sm.w};
            #pragma unroll
            for (int o=0;o<4;++o) {
                float v = wpw[o*4+0]*g0 + wpw[o*4+1]*g1 + wpw[o*4+2]*g2 + wpw[o*4+3]*g3;
                abf[p*128 + o*25 + k] = __float2bfloat16(gelu1(v) * smv[o]);
            }
            mtL[t] = sm.x + sm.y + sm.z + sm.w;
        }
    }
    __syncthreads();

    // ---- phase 4: copy abf -> global (coalesced), m_patch ----
    {
        const float4* src = (const float4*)abf;
        float4* dst = (float4*)(xs_out + (size_t)(b*2000 + tile*20)*128);
        #pragma unroll
        for (int it = 0; it < 2; ++it) {
            int idx = tid + it*256;
            if (idx < 320) dst[idx] = src[idx];
        }
    }
    if (tid < 20) {
        int cnt = 0;
        #pragma unroll
        for (int k=0;k<25;++k) cnt += (mtL[tid*25+k] > 0.f) ? 1 : 0;
        mpatch[(size_t)b*2000 + tile*20 + tid] = (cnt >= 3) ? 1.f : 0.f;
    }
}

// ---------------- kernel 2: MFMA patch projection (M=128000, N=160, K=128) + LayerNorm ----
// No LDS, no barriers: each wave = 16 patches x 160 d. W frags from global (L1-resident).
__global__ __launch_bounds__(256, 4) void k_proj(
    const __hip_bfloat16* __restrict__ wbf, const __hip_bfloat16* __restrict__ xsg,
    const float* __restrict__ gamma, const float* __restrict__ beta,
    float* __restrict__ hout)
{
    const int tid  = threadIdx.x;
    const int wv   = tid >> 6, lane = tid & 63;
    const int n    = lane & 15, quad = lane >> 4;
    const int p0   = (blockIdx.x*4 + wv) * 16;

    const unsigned short* Wp = (const unsigned short*)wbf;
    const unsigned short* Ap = (const unsigned short*)xsg;

    bf16x8 af[4];
    #pragma unroll
    for (int kk=0;kk<4;++kk)
        af[kk] = *(const bf16x8*)(Ap + (size_t)(p0 + n)*128 + kk*32 + quad*8);

    float gm[10], bt_[10];
    #pragma unroll
    for (int t = 0; t < 10; ++t) { gm[t] = gamma[t*16 + n]; bt_[t] = beta[t*16 + n]; }

    f32x4 acc[10];
    #pragma unroll
    for (int t = 0; t < 10; ++t) acc[t] = (f32x4){0.f,0.f,0.f,0.f};
    #pragma unroll
    for (int kk = 0; kk < 4; ++kk) {
        #pragma unroll
        for (int t = 0; t < 10; ++t) {
            bf16x8 bf = *(const bf16x8*)(Wp + (size_t)(t*16 + n)*128 + kk*32 + quad*8);
            acc[t] = __builtin_amdgcn_mfma_f32_16x16x32_bf16(af[kk], bf, acc[t], 0, 0, 0);
        }
    }

    // LayerNorm in registers: C/D layout row(patch)=quad*4+r, col(d)=t*16+n
    float mu[4], rs[4];
    #pragma unroll
    for (int r = 0; r < 4; ++r) {
        float a = 0.f;
        #pragma unroll
        for (int t = 0; t < 10; ++t) a += acc[t][r];
        a += __shfl_xor(a, 1, 64); a += __shfl_xor(a, 2, 64);
        a += __shfl_xor(a, 4, 64); a += __shfl_xor(a, 8, 64);
        mu[r] = a * (1.f/160.f);
    }
    #pragma unroll
    for (int r = 0; r < 4; ++r) {
        float q = 0.f;
        #pragma unroll
        for (int t = 0; t < 10; ++t) { float dv = acc[t][r] - mu[r]; q = fmaf(dv, dv, q); }
        q += __shfl_xor(q, 1, 64); q += __shfl_xor(q, 2, 64);
        q += __shfl_xor(q, 4, 64); q += __shfl_xor(q, 8, 64);
        rs[r] = rsqrtf(q * (1.f/160.f) + 1e-5f);
    }
    const int prow = p0 + quad*4;
    #pragma unroll
    for (int t = 0; t < 10; ++t) {
        #pragma unroll
        for (int r = 0; r < 4; ++r) {
            hout[(size_t)(prow + r)*160 + t*16 + n] = (acc[t][r] - mu[r])*rs[r]*gm[t] + bt_[t];
        }
    }
}

extern "C" void kernel_launch(void* const* d_in, const int* in_sizes, int n_in,
                              void* d_out, int out_size, void* d_ws, size_t ws_size,
                              hipStream_t stream) {
    const float* X     = (const float*)d_in[0];
    const float* M     = (const float*)d_in[1];
    const float* w_env = (const float*)d_in[2];
    const float* w_bur = (const float*)d_in[3];
    const float* syn   = (const float*)d_in[4];
    const float* wdw   = (const float*)d_in[5];
    const float* wpw   = (const float*)d_in[6];
    const float* wproj = (const float*)d_in[7];
    const float* gam   = (const float*)d_in[8];
    const float* bet   = (const float*)d_in[9];

    float* h      = (float*)d_out;                       // (64,2000,160)
    float* mpatch = h + (size_t)64*2000*160;             // (64,2000)

    __hip_bfloat16* wbf = (__hip_bfloat16*)d_ws;                          // 40 KB
    __hip_bfloat16* xsb = (__hip_bfloat16*)((char*)d_ws + 65536);         // 128000*128*2 = 32.8 MB

    k_cvtw<<<80, 256, 0, stream>>>(wproj, wbf);
    k_pre<<<6400, 256, 0, stream>>>(X, M, w_env, w_bur, syn, wdw, wpw, xsb, mpatch);
    k_proj<<<2000, 256, 0, stream>>>(wbf, xsb, gam, bet, h);
}

// Round 5
// 287.106 us; speedup vs baseline: 1.8716x; 1.8716x over previous
//
#include <hip/hip_runtime.h>
#include <hip/hip_bf16.h>
#include <cstddef>

#define T_LEN 50000

typedef __attribute__((ext_vector_type(8))) short bf16x8;
typedef __attribute__((ext_vector_type(4))) float f32x4;

__device__ __forceinline__ float sp_(float x){ return (x > 20.f) ? x : log1pf(expf(x)); }
__device__ __forceinline__ float gelu1(float x){ return 0.5f*x*(1.f + erff(x*0.7071067811865475f)); }

// ---------------- kernel 0: w_proj [160][100] fp32 -> wfrag bf16 in MFMA B-fragment order ----
// chunk layout: [t][kk][quad][n][j], element = W[t*16+n][kk*32+quad*8+j] (K zero-padded to 128)
__global__ void k_cvtw(const float* __restrict__ wproj, __hip_bfloat16* __restrict__ wfrag)
{
    int idx = blockIdx.x*256 + threadIdx.x;
    if (idx < 160*128) {
        int j    = idx & 7;
        int n    = (idx >> 3) & 15;
        int quad = (idx >> 7) & 3;
        int kk   = (idx >> 9) & 3;
        int t    = idx >> 11;
        int row  = t*16 + n;
        int col  = kk*32 + quad*8 + j;
        float v  = (col < 100) ? wproj[row*100 + col] : 0.f;
        wfrag[idx] = __float2bfloat16(v);
    }
}

// ---------------- kernel 1: preprocessing chain -> xs bf16 [patch][128] + m_patch ----------
// block: 256 threads, tile = 500 t (20 patches), 2 t/thread. grid = 64*100.
// LDS 21.6 KB (abf/mtL alias the dead xb region). Single-arg LB: natural VGPR (~108), NO cap
// (R4 lesson: a min-waves arg below natural usage -> spills -> 1.28 GB scratch traffic).
__global__ __launch_bounds__(256) void k_pre(
    const float* __restrict__ X, const float* __restrict__ Mq,
    const float* __restrict__ w_env, const float* __restrict__ w_bur,
    const float* __restrict__ syn, const float* __restrict__ wdw,
    const float* __restrict__ wpw,
    __hip_bfloat16* __restrict__ xs_out, float* __restrict__ mpatch)
{
    __shared__ __align__(16) char smem[21664];
    float4* xb            = (float4*)smem;                 // [665]: 532 entries, +1-per-4 pad
    float4* s1b           = (float4*)(smem + 10640);       // [635]: 508 entries padded
    unsigned char* maskb  = (unsigned char*)(smem + 20800);// [532]
    float* WnL            = (float*)(smem + 21344);        // [16]
    float4* SmLUT         = (float4*)(smem + 21408);       // [16]
    // aliases valid after phase 2 (xb dead):
    __hip_bfloat16* abf   = (__hip_bfloat16*)smem;         // [20*128]
    float* mtL            = (float*)(smem + 5120);         // [500]

    const int tid  = threadIdx.x;
    const int b    = blockIdx.x / 100;
    const int tile = blockIdx.x % 100;
    const int t0   = tile * 500;

    // ---- phase 1: load x = X*M (float4 over channels) into xb, build mask ----
    const float4* X4 = (const float4*)X + (size_t)b * T_LEN;
    const float4* M4 = (const float4*)Mq + (size_t)b * T_LEN;
    #pragma unroll
    for (int jj = 0; jj < 3; ++jj) {
        int idx = tid + jj*256;
        if (idx < 532) {
            int t = t0 - 16 + idx;
            float4 xv = make_float4(0.f,0.f,0.f,0.f);
            unsigned mk = 0u;
            if (t >= 0 && t < T_LEN) {
                float4 a = X4[t], m = M4[t];
                xv = make_float4(a.x*m.x, a.y*m.y, a.z*m.z, a.w*m.w);
                mk = (m.x>0.f?1u:0u) | (m.y>0.f?2u:0u) | (m.z>0.f?4u:0u) | (m.w>0.f?8u:0u);
            }
            xb[idx + (idx>>2)] = xv;
            maskb[idx] = (unsigned char)mk;
        }
    }
    if (tid < 4) {
        float w0 = sp_(syn[tid*4+0]), w1 = sp_(syn[tid*4+1]);
        float w2 = sp_(syn[tid*4+2]), w3 = sp_(syn[tid*4+3]);
        float inv = 1.f / fmaxf(w0+w1+w2+w3, 1e-6f);
        WnL[tid*4+0]=w0*inv; WnL[tid*4+1]=w1*inv; WnL[tid*4+2]=w2*inv; WnL[tid*4+3]=w3*inv;
    }
    __syncthreads();
    if (tid < 16) {
        float sm[4];
        #pragma unroll
        for (int m=0;m<4;++m) {
            float a = 0.f;
            #pragma unroll
            for (int c=0;c<4;++c) if (tid & (1<<c)) a += WnL[m*4+c];
            sm[m] = fminf(a, 1.f);
        }
        SmLUT[tid] = make_float4(sm[0],sm[1],sm[2],sm[3]);
    }
    __syncthreads();

    // ---- phase 2: env/burst/xm -> S1 for t in [t0-4, t0+504), 2 t/thread ----
    if (tid < 254) {
        float4 env[2], bur[2], xk[2];
        #pragma unroll
        for (int j=0;j<2;++j){ env[j]=make_float4(0,0,0,0); bur[j]=make_float4(0,0,0,0); }
        float4 xprev = make_float4(0,0,0,0);
        const int base  = 2*tid;
        const int gbase = t0 - 4 + base;
        #pragma unroll
        for (int s = -12; s <= 13; ++s) {
            int lt = base + (s+12);
            float4 xc = xb[lt + (lt>>2)];
            float4 ax = make_float4(fabsf(xc.x),fabsf(xc.y),fabsf(xc.z),fabsf(xc.w));
            if (s >= -4 && s <= 5) {
                int g = gbase + s;
                float4 dx;
                if (g <= 0 || g >= T_LEN) dx = make_float4(0,0,0,0);
                else dx = make_float4(xc.x-xprev.x, xc.y-xprev.y, xc.z-xprev.z, xc.w-xprev.w);
                float4 adx = make_float4(fabsf(dx.x),fabsf(dx.y),fabsf(dx.z),fabsf(dx.w));
                #pragma unroll
                for (int j=0;j<2;++j) {
                    int bk = s + 4 - j;
                    if (bk >= 0 && bk < 9) {
                        float b0=w_bur[bk], b1=w_bur[9+bk], b2=w_bur[18+bk], b3=w_bur[27+bk];
                        bur[j].x = fmaf(b0, adx.x, bur[j].x);
                        bur[j].y = fmaf(b1, adx.y, bur[j].y);
                        bur[j].z = fmaf(b2, adx.z, bur[j].z);
                        bur[j].w = fmaf(b3, adx.w, bur[j].w);
                    }
                }
            }
            #pragma unroll
            for (int j=0;j<2;++j) {
                int k = s + 12 - j;
                if (k >= 0 && k < 25) {
                    float e0=w_env[k], e1=w_env[25+k], e2=w_env[50+k], e3=w_env[75+k];
                    env[j].x = fmaf(e0, ax.x, env[j].x);
                    env[j].y = fmaf(e1, ax.y, env[j].y);
                    env[j].z = fmaf(e2, ax.z, env[j].z);
                    env[j].w = fmaf(e3, ax.w, env[j].w);
                }
            }
            if (s >= 0 && s <= 1) xk[s] = xc;
            xprev = xc;
        }
        #pragma unroll
        for (int j=0;j<2;++j) {
            int g = gbase + j;
            float4 xm = make_float4(
                0.9f*env[j].x + 0.6f*bur[j].x + 0.2f*xk[j].x,
                0.9f*env[j].y + 0.6f*bur[j].y + 0.2f*xk[j].y,
                0.9f*env[j].z + 0.6f*bur[j].z + 0.2f*xk[j].z,
                0.9f*env[j].w + 0.6f*bur[j].w + 0.2f*xk[j].w);
            float4 out = make_float4(0,0,0,0);
            if (g >= 0 && g < T_LEN) {
                out.x = WnL[0]*xm.x  + WnL[1]*xm.y  + WnL[2]*xm.z  + WnL[3]*xm.w;
                out.y = WnL[4]*xm.x  + WnL[5]*xm.y  + WnL[6]*xm.z  + WnL[7]*xm.w;
                out.z = WnL[8]*xm.x  + WnL[9]*xm.y  + WnL[10]*xm.z + WnL[11]*xm.w;
                out.w = WnL[12]*xm.x + WnL[13]*xm.y + WnL[14]*xm.z + WnL[15]*xm.w;
            }
            int ls = base + j;
            s1b[ls + (ls>>2)] = out;
        }
    }
    __syncthreads();   // xb dead from here; abf/mtL aliases become valid

    // ---- phase 3: pre-dw + gelu + pw + gelu, * Sm -> abf (bf16 A-layout); mtL ----
    for (int idx = tid; idx < 20*28; idx += 256) {   // zero K-pad i in [100,128)
        int p = idx / 28, i = 100 + idx % 28;
        abf[p*128 + i] = __float2bfloat16(0.f);
    }
    if (tid < 250) {
        float4 s2a[2];
        #pragma unroll
        for (int j=0;j<2;++j) s2a[j]=make_float4(0,0,0,0);
        const int base = 2*tid;
        #pragma unroll
        for (int s = -4; s <= 5; ++s) {
            int ls = base + s + 4;
            float4 sc = s1b[ls + (ls>>2)];
            #pragma unroll
            for (int j=0;j<2;++j) {
                int k = s + 4 - j;
                if (k >= 0 && k < 9) {
                    float d0=wdw[k], d1=wdw[9+k], d2=wdw[18+k], d3=wdw[27+k];
                    s2a[j].x = fmaf(d0, sc.x, s2a[j].x);
                    s2a[j].y = fmaf(d1, sc.y, s2a[j].y);
                    s2a[j].z = fmaf(d2, sc.z, s2a[j].z);
                    s2a[j].w = fmaf(d3, sc.w, s2a[j].w);
                }
            }
        }
        #pragma unroll
        for (int j=0;j<2;++j) {
            int t = base + j;              // local t in [0,500)
            float g0 = gelu1(s2a[j].x), g1 = gelu1(s2a[j].y);
            float g2 = gelu1(s2a[j].z), g3 = gelu1(s2a[j].w);
            float4 sm = SmLUT[maskb[t + 16]];
            int p = t / 25, k = t % 25;
            float smv[4] = {sm.x, sm.y, sm.z, sm.w};
            #pragma unroll
            for (int o=0;o<4;++o) {
                float v = wpw[o*4+0]*g0 + wpw[o*4+1]*g1 + wpw[o*4+2]*g2 + wpw[o*4+3]*g3;
                abf[p*128 + o*25 + k] = __float2bfloat16(gelu1(v) * smv[o]);
            }
            mtL[t] = sm.x + sm.y + sm.z + sm.w;
        }
    }
    __syncthreads();

    // ---- phase 4: copy abf -> global (coalesced), m_patch ----
    {
        const float4* src = (const float4*)abf;
        float4* dst = (float4*)(xs_out + (size_t)(b*2000 + tile*20)*128);
        #pragma unroll
        for (int it = 0; it < 2; ++it) {
            int idx = tid + it*256;
            if (idx < 320) dst[idx] = src[idx];
        }
    }
    if (tid < 20) {
        int cnt = 0;
        #pragma unroll
        for (int k=0;k<25;++k) cnt += (mtL[tid*25+k] > 0.f) ? 1 : 0;
        mpatch[(size_t)b*2000 + tile*20 + tid] = (cnt >= 3) ? 1.f : 0.f;
    }
}

// ---------------- kernel 2: MFMA patch projection (M=128000, N=160, K=128) + LayerNorm ----
// W staged once per block into LDS in fragment order (conflict-floor ds_read_b128: lane i
// reads contiguous chunk i). Each wave: 4 independent tiles of 16 patches. Grid 500.
__global__ __launch_bounds__(256) void k_proj(
    const __hip_bfloat16* __restrict__ wfrag, const __hip_bfloat16* __restrict__ xsg,
    const float* __restrict__ gamma, const float* __restrict__ beta,
    float* __restrict__ hout)
{
    __shared__ __align__(16) unsigned short Wl[160*128];   // 40 KB, fragment order
    const int tid  = threadIdx.x;
    const int wv   = tid >> 6, lane = tid & 63;
    const int n    = lane & 15, quad = lane >> 4;

    {   // tid-linear coalesced stage: 2560 float4
        const float4* wg = (const float4*)wfrag;
        float4* wl4 = (float4*)Wl;
        #pragma unroll
        for (int it = 0; it < 10; ++it) wl4[tid + it*256] = wg[tid + it*256];
    }
    float gm[10], bt_[10];
    #pragma unroll
    for (int t = 0; t < 10; ++t) { gm[t] = gamma[t*16 + n]; bt_[t] = beta[t*16 + n]; }
    __syncthreads();

    const unsigned short* Ap = (const unsigned short*)xsg;

    for (int tile = 0; tile < 4; ++tile) {
        const int p0 = ((blockIdx.x*4 + wv)*4 + tile) * 16;

        bf16x8 af[4];
        #pragma unroll
        for (int kk=0;kk<4;++kk)
            af[kk] = *(const bf16x8*)(Ap + (size_t)(p0 + n)*128 + kk*32 + quad*8);

        f32x4 acc[10];
        #pragma unroll
        for (int t = 0; t < 10; ++t) acc[t] = (f32x4){0.f,0.f,0.f,0.f};
        #pragma unroll
        for (int kk = 0; kk < 4; ++kk) {
            #pragma unroll
            for (int t = 0; t < 10; ++t) {
                bf16x8 bf = *(const bf16x8*)(Wl + ((t*4 + kk)*64 + lane)*8);
                acc[t] = __builtin_amdgcn_mfma_f32_16x16x32_bf16(af[kk], bf, acc[t], 0, 0, 0);
            }
        }

        // LayerNorm in registers: C/D layout row(patch)=quad*4+r, col(d)=t*16+n
        float mu[4], rs[4];
        #pragma unroll
        for (int r = 0; r < 4; ++r) {
            float a = 0.f;
            #pragma unroll
            for (int t = 0; t < 10; ++t) a += acc[t][r];
            a += __shfl_xor(a, 1, 64); a += __shfl_xor(a, 2, 64);
            a += __shfl_xor(a, 4, 64); a += __shfl_xor(a, 8, 64);
            mu[r] = a * (1.f/160.f);
        }
        #pragma unroll
        for (int r = 0; r < 4; ++r) {
            float q = 0.f;
            #pragma unroll
            for (int t = 0; t < 10; ++t) { float dv = acc[t][r] - mu[r]; q = fmaf(dv, dv, q); }
            q += __shfl_xor(q, 1, 64); q += __shfl_xor(q, 2, 64);
            q += __shfl_xor(q, 4, 64); q += __shfl_xor(q, 8, 64);
            rs[r] = rsqrtf(q * (1.f/160.f) + 1e-5f);
        }
        const int prow = p0 + quad*4;
        #pragma unroll
        for (int t = 0; t < 10; ++t) {
            #pragma unroll
            for (int r = 0; r < 4; ++r) {
                hout[(size_t)(prow + r)*160 + t*16 + n] = (acc[t][r] - mu[r])*rs[r]*gm[t] + bt_[t];
            }
        }
    }
}

extern "C" void kernel_launch(void* const* d_in, const int* in_sizes, int n_in,
                              void* d_out, int out_size, void* d_ws, size_t ws_size,
                              hipStream_t stream) {
    const float* X     = (const float*)d_in[0];
    const float* M     = (const float*)d_in[1];
    const float* w_env = (const float*)d_in[2];
    const float* w_bur = (const float*)d_in[3];
    const float* syn   = (const float*)d_in[4];
    const float* wdw   = (const float*)d_in[5];
    const float* wpw   = (const float*)d_in[6];
    const float* wproj = (const float*)d_in[7];
    const float* gam   = (const float*)d_in[8];
    const float* bet   = (const float*)d_in[9];

    float* h      = (float*)d_out;                       // (64,2000,160)
    float* mpatch = h + (size_t)64*2000*160;             // (64,2000)

    __hip_bfloat16* wbf = (__hip_bfloat16*)d_ws;                          // 40 KB (frag order)
    __hip_bfloat16* xsb = (__hip_bfloat16*)((char*)d_ws + 65536);         // 128000*128*2 = 32.8 MB

    k_cvtw<<<80, 256, 0, stream>>>(wproj, wbf);
    k_pre<<<6400, 256, 0, stream>>>(X, M, w_env, w_bur, syn, wdw, wpw, xsb, mpatch);
    k_proj<<<500, 256, 0, stream>>>(wbf, xsb, gam, bet, h);
}